// Round 2
// baseline (520.389 us; speedup 1.0000x reference)
//
#include <hip/hip_runtime.h>
#include <hip/hip_bf16.h>

#define Nn 8192
#define Dd 512
#define KK 16
#define CC 32      // candidates kept per partial list / merged list
#define TI 128
#define TJ 128
#define BKc 64
#define JSPLIT 8
#define JTILES (Nn / JSPLIT / TJ)   // 8
#define PARTS (JSPLIT * 2)          // 16 partial lists per row

typedef short bf16x8 __attribute__((ext_vector_type(8)));
typedef float f32x4 __attribute__((ext_vector_type(4)));
typedef unsigned int uint32;

// Insert v into a descending-sorted 32-entry register array (h[0] = largest).
// Precondition: v < h[0]. Single bubble pass restores sorted order.
__device__ __forceinline__ void heap_insert32(uint32* h, uint32 v) {
  h[0] = v;
#pragma unroll
  for (int s = 0; s < CC - 1; ++s) {
    uint32 a = h[s], b = h[s + 1];
    uint32 mx = a > b ? a : b;
    uint32 mn = a > b ? b : a;
    h[s] = mx;
    h[s + 1] = mn;
  }
}

// Async global->LDS, 16B per lane. LDS dest must be wave-uniform base (+lane*16 is HW-applied).
__device__ __forceinline__ void gload_lds16(const void* g, void* l) {
  __builtin_amdgcn_global_load_lds(
      (const __attribute__((address_space(1))) unsigned int*)g,
      (__attribute__((address_space(3))) unsigned int*)l, 16, 0, 0);
}

// ---------------- Kernel A: fp32 -> bf16 copy + row sq-norms ----------------
__global__ void knn_prep(const float* __restrict__ x, uint32* __restrict__ xbu,
                         float* __restrict__ sq) {
  const int row = blockIdx.x * 4 + (threadIdx.x >> 6);
  const int l = threadIdx.x & 63;
  const float2* xr = (const float2*)(x + (size_t)row * Dd);
  float s = 0.f;
#pragma unroll
  for (int q = 0; q < 4; ++q) {
    float2 v = xr[q * 64 + l];
    s = fmaf(v.x, v.x, s);
    s = fmaf(v.y, v.y, s);
    uint32 ux = __builtin_bit_cast(uint32, v.x);
    uint32 uy = __builtin_bit_cast(uint32, v.y);
    uint32 bx = (ux + 0x7FFFu + ((ux >> 16) & 1u)) >> 16;  // RNE to bf16
    uint32 by = (uy + 0x7FFFu + ((uy >> 16) & 1u)) >> 16;
    xbu[(size_t)row * (Dd / 2) + q * 64 + l] = bx | (by << 16);
  }
#pragma unroll
  for (int off = 32; off > 0; off >>= 1) s += __shfl_down(s, off);
  if (l == 0) sq[row] = s;
}

// ------- Kernel B: fused bf16-MFMA Gram tile + per-row top-32 candidates -------
// LDS A/B tiles: linear dest (global_load_lds) + XOR-swizzled SOURCE column,
// fragment reads apply the same involution: byte ^= (row&7)<<4 within 128B row.
// d2s: [128][32] f32, 16B-chunk swizzle chunk' = chunk ^ (row&7).
__global__ __launch_bounds__(256, 2) void knn_cand(
    const unsigned short* __restrict__ xb, const float* __restrict__ sq,
    uint32* __restrict__ partials) {
  __shared__ unsigned short ALds[TI * BKc];  // 16 KB
  __shared__ unsigned short BLds[TJ * BKc];  // 16 KB
  __shared__ float d2s[TI][32];              // 16 KB (one 32-col phase at a time)
  __shared__ float sqj[TJ];

  const int bid = blockIdx.x;
  const int ib = bid & 63;  // 64 I-tiles
  const int jc = bid >> 6;  // 8 J-chunks
  const int t = threadIdx.x;
  const int w = t >> 6;
  const int l = t & 63;
  const int wrow = w >> 1, wcol = w & 1;
  const int l16 = l & 15, lq = l >> 4;

  const int row_s = t >> 1;  // scan: thread's row within tile
  const int hv = t & 1;      // scan: which 16-col half of each phase
  const int irow_g = ib * TI + row_s;

  uint32 heap[CC];
#pragma unroll
  for (int s = 0; s < CC; ++s) heap[s] = 0xFFFFFFFFu;

  for (int jt = 0; jt < JTILES; ++jt) {
    const int jbase = jc * (Nn / JSPLIT) + jt * TJ;
    __syncthreads();  // previous scan's sqj/d2s reads done
    if (t < TJ) sqj[t] = sq[jbase + t];

    f32x4 acc[4][4];
#pragma unroll
    for (int a = 0; a < 4; ++a)
#pragma unroll
      for (int b = 0; b < 4; ++b) acc[a][b] = (f32x4){0.f, 0.f, 0.f, 0.f};

    for (int kk = 0; kk < Dd / BKc; ++kk) {
      __syncthreads();  // LDS reads of previous chunk done
#pragma unroll
      for (int u = 0; u < 4; ++u) {
        const int ch = w * 4 + u;          // wave-uniform chunk id (1KB each)
        const int r = ch * 8 + (l >> 3);   // row within tile
        const int cs = ((l & 7) ^ (r & 7)) * 8;  // pre-swizzled source col (bf16)
        gload_lds16(xb + (size_t)(ib * TI + r) * Dd + kk * BKc + cs,
                    (void*)(ALds + ch * 512));
        gload_lds16(xb + (size_t)(jbase + r) * Dd + kk * BKc + cs,
                    (void*)(BLds + ch * 512));
      }
      __syncthreads();  // staging complete (vmcnt drained by barrier)
#pragma unroll
      for (int ks = 0; ks < 2; ++ks) {
        bf16x8 af[4], bfr[4];
#pragma unroll
        for (int fi = 0; fi < 4; ++fi) {
          const int R = wrow * 64 + fi * 16 + l16;
          af[fi] = *(const bf16x8*)&ALds[R * BKc +
                                         ((ks * 32 + lq * 8) ^ ((R & 7) * 8))];
        }
#pragma unroll
        for (int fj = 0; fj < 4; ++fj) {
          const int R = wcol * 64 + fj * 16 + l16;
          bfr[fj] = *(const bf16x8*)&BLds[R * BKc +
                                          ((ks * 32 + lq * 8) ^ ((R & 7) * 8))];
        }
#pragma unroll
        for (int fi = 0; fi < 4; ++fi)
#pragma unroll
          for (int fj = 0; fj < 4; ++fj)
            acc[fi][fj] = __builtin_amdgcn_mfma_f32_16x16x32_bf16(
                af[fi], bfr[fj], acc[fi][fj], 0, 0, 0);
      }
    }

    // Four 32-col phases: stage dot products to LDS (chunk-swizzled), scan.
#pragma unroll
    for (int p = 0; p < 4; ++p) {
      __syncthreads();  // previous phase's scan reads done
      if (wcol == (p >> 1)) {
        const int fjp = p & 1;
#pragma unroll
        for (int fi = 0; fi < 4; ++fi)
#pragma unroll
          for (int fjh = 0; fjh < 2; ++fjh) {
            const int fj = fjp * 2 + fjh;
#pragma unroll
            for (int r = 0; r < 4; ++r) {
              const int row = wrow * 64 + fi * 16 + lq * 4 + r;
              const int c = fjh * 16 + l16;
              const int cs2 = (((c >> 2) ^ (row & 7)) << 2) | (c & 3);
              d2s[row][cs2] = acc[fi][fj][r];
            }
          }
      }
      __syncthreads();
      const uint32 jg0 = (uint32)(jbase + p * 32);
#pragma unroll
      for (int u2 = 0; u2 < 4; ++u2) {
        const int chunk = (hv * 4 + u2) ^ (row_s & 7);
        float4 v = *(const float4*)&d2s[row_s][chunk * 4];
        float vv[4] = {v.x, v.y, v.z, v.w};
#pragma unroll
        for (int e = 0; e < 4; ++e) {
          const int jj = hv * 16 + u2 * 4 + e;
          const uint32 jg = jg0 + jj;
          // key = d2 - sq_i (constant per row dropped): sq_j - 2*dot
          float key = fmaf(-2.f, vv[e], sqj[p * 32 + jj]);
          uint32 ub = __builtin_bit_cast(uint32, key);
          uint32 m = ub ^ ((ub >> 31) ? 0xFFFFFFFFu : 0x80000000u);  // order-preserving
          uint32 packed = (m & 0xFFFFE000u) | jg;                    // 13-bit index
          if (jg == (uint32)irow_g) packed = 0xFFFFFFFFu;            // exclude self
          if (packed < heap[0]) heap_insert32(heap, packed);
        }
      }
    }
  }

  const int part = jc * 2 + hv;
#pragma unroll
  for (int s = 0; s < CC; ++s)
    partials[(size_t)(part * CC + s) * Nn + irow_g] = heap[s];
}

// ---------------- Kernel C: merge 16 partial lists -> top-32 per row ----------------
__global__ void knn_merge(const uint32* __restrict__ partials,
                          int* __restrict__ cand) {
  const int row = blockIdx.x * 256 + threadIdx.x;
  uint32 heap[CC];
#pragma unroll
  for (int s = 0; s < CC; ++s) heap[s] = 0xFFFFFFFFu;
  for (int p = 0; p < PARTS * CC; ++p) {
    uint32 v = partials[(size_t)p * Nn + row];
    if (v < heap[0]) heap_insert32(heap, v);
  }
#pragma unroll
  for (int s = 0; s < CC; ++s)
    cand[(size_t)row * CC + s] = (int)(heap[s] & 0x1FFFu);
}

// ------- Kernel D: exact fp64 rescore of 32 candidates -> top-16 -> average -------
// Candidate rows cached in LDS during the d2 pass (float4 loads); the final
// average reads LDS, not global (saves the 32KB/row re-gather).
__global__ __launch_bounds__(256) void knn_rescore(
    const float* __restrict__ x, const int* __restrict__ cand,
    float* __restrict__ out) {
  __shared__ float rowsS[CC][Dd];  // 64 KB
  __shared__ int candS[CC];
  __shared__ double d2S[CC];
  __shared__ int selS[KK];
  const int row = blockIdx.x;
  const int t = threadIdx.x, w = t >> 6, l = t & 63;
  if (t < CC) candS[t] = cand[(size_t)row * CC + t];
  __syncthreads();
  const float4* x4 = (const float4*)x;
  float4 xi[2];
#pragma unroll
  for (int q = 0; q < 2; ++q) xi[q] = x4[(size_t)row * 128 + q * 64 + l];
  for (int u = 0; u < 8; ++u) {
    const int c = w * 8 + u;
    const int j = candS[c];
    double s = 0.0;
#pragma unroll
    for (int q = 0; q < 2; ++q) {
      float4 vb = x4[(size_t)j * 128 + q * 64 + l];
      *(float4*)&rowsS[c][(q * 64 + l) * 4] = vb;
      double d0 = (double)xi[q].x - (double)vb.x;
      double d1 = (double)xi[q].y - (double)vb.y;
      double d2 = (double)xi[q].z - (double)vb.z;
      double d3 = (double)xi[q].w - (double)vb.w;
      s = fma(d0, d0, s);
      s = fma(d1, d1, s);
      s = fma(d2, d2, s);
      s = fma(d3, d3, s);
    }
#pragma unroll
    for (int off = 32; off > 0; off >>= 1) s += __shfl_down(s, off);
    if (l == 0) d2S[c] = s;
  }
  __syncthreads();
  if (t < CC) {
    const double mine = d2S[t];
    const int mi = candS[t];
    int rank = 0;
#pragma unroll
    for (int o = 0; o < CC; ++o) {
      double vo = d2S[o];
      int io = candS[o];
      if (vo < mine || (vo == mine && io < mi)) rank++;
    }
    if (rank < KK) selS[rank] = t;  // slot index into rowsS
  }
  __syncthreads();
#pragma unroll
  for (int h = 0; h < 2; ++h) {
    const int d = t + h * 256;
    float a = 0.f;
#pragma unroll
    for (int n = 0; n < KK; ++n) a += rowsS[selS[n]][d];
    out[(size_t)row * Dd + d] = a * 0.0625f;
  }
}

extern "C" void kernel_launch(void* const* d_in, const int* in_sizes, int n_in,
                              void* d_out, int out_size, void* d_ws,
                              size_t ws_size, hipStream_t stream) {
  const float* x = (const float*)d_in[0];
  float* out = (float*)d_out;
  char* ws = (char*)d_ws;
  // ws layout: xb (8MB) | sq (32KB) | partials (16MB) | cand (1MB)  => ~25.2MB
  unsigned short* xb = (unsigned short*)ws;
  float* sq = (float*)(ws + (size_t)Nn * Dd * 2);
  uint32* partials = (uint32*)(ws + (size_t)Nn * Dd * 2 + (size_t)Nn * 4);
  int* cand = (int*)((char*)partials + (size_t)PARTS * CC * Nn * 4);

  knn_prep<<<Nn / 4, 256, 0, stream>>>(x, (uint32*)xb, sq);
  knn_cand<<<64 * JSPLIT, 256, 0, stream>>>(xb, sq, partials);
  knn_merge<<<Nn / 256, 256, 0, stream>>>(partials, cand);
  knn_rescore<<<Nn, 256, 0, stream>>>(x, cand, out);
}

// Round 3
// 292.001 us; speedup vs baseline: 1.7821x; 1.7821x over previous
//
#include <hip/hip_runtime.h>
#include <hip/hip_bf16.h>

#define Nn 8192
#define Dd 512
#define KK 16
#define CC 32      // merged candidates per row (rescore input)
#define CSUB 16    // candidates kept per substream reservoir
#define TI 128
#define TJ 128
#define BKc 64
#define JSPLIT 8
#define JTILES (Nn / JSPLIT / TJ)   // 8
#define NPART (JSPLIT * 2)          // 16 (jc,hv) substream pairs -> 32 substreams
#define PART_ENTRIES (NPART * 2 * CSUB)  // 512 entries per row in partials

typedef short bf16x8 __attribute__((ext_vector_type(8)));
typedef float f32x4 __attribute__((ext_vector_type(4)));
typedef unsigned int uint32;

__device__ __forceinline__ uint32 med3u(uint32 a, uint32 b, uint32 c) {
  uint32 d;
  asm("v_med3_u32 %0, %1, %2, %3" : "=v"(d) : "v"(a), "v"(b), "v"(c));
  return d;
}

// Branchless top-k (smallest keys) in a descending-sorted register array.
// h[0] = largest kept. Insert v, drop max(v, h[0]) -- one med3 per slot,
// correct for ALL v (v >= h[0] leaves list unchanged). No divergence.
template <int CCn>
__device__ __forceinline__ void topk_insert(uint32* h, uint32 v) {
#pragma unroll
  for (int s = 0; s < CCn - 1; ++s) h[s] = med3u(h[s], h[s + 1], v);
  h[CCn - 1] = (h[CCn - 1] < v) ? h[CCn - 1] : v;
}

// Async global->LDS, 16B per lane. LDS dest must be wave-uniform base (+lane*16 HW-applied).
__device__ __forceinline__ void gload_lds16(const void* g, void* l) {
  __builtin_amdgcn_global_load_lds(
      (const __attribute__((address_space(1))) unsigned int*)g,
      (__attribute__((address_space(3))) unsigned int*)l, 16, 0, 0);
}

// ---------------- Kernel A: fp32 -> bf16 copy + row sq-norms ----------------
__global__ void knn_prep(const float* __restrict__ x, uint32* __restrict__ xbu,
                         float* __restrict__ sq) {
  const int row = blockIdx.x * 4 + (threadIdx.x >> 6);
  const int l = threadIdx.x & 63;
  const float2* xr = (const float2*)(x + (size_t)row * Dd);
  float s = 0.f;
#pragma unroll
  for (int q = 0; q < 4; ++q) {
    float2 v = xr[q * 64 + l];
    s = fmaf(v.x, v.x, s);
    s = fmaf(v.y, v.y, s);
    uint32 ux = __builtin_bit_cast(uint32, v.x);
    uint32 uy = __builtin_bit_cast(uint32, v.y);
    uint32 bx = (ux + 0x7FFFu + ((ux >> 16) & 1u)) >> 16;  // RNE to bf16
    uint32 by = (uy + 0x7FFFu + ((uy >> 16) & 1u)) >> 16;
    xbu[(size_t)row * (Dd / 2) + q * 64 + l] = bx | (by << 16);
  }
#pragma unroll
  for (int off = 32; off > 0; off >>= 1) s += __shfl_down(s, off);
  if (l == 0) sq[row] = s;
}

// ------- Kernel B: fused bf16-MFMA Gram tile + per-substream top-16 -------
__global__ __launch_bounds__(256, 3) void knn_cand(
    const unsigned short* __restrict__ xb, const float* __restrict__ sq,
    uint32* __restrict__ partials) {
  __shared__ unsigned short ALds[TI * BKc];  // 16 KB
  __shared__ unsigned short BLds[TJ * BKc];  // 16 KB
  __shared__ float d2s[TI][32];              // 16 KB (one 32-col phase)
  __shared__ float sqj[TJ];

  const int bid = blockIdx.x;
  const int ib = bid & 63;  // 64 I-tiles
  const int jc = bid >> 6;  // 8 J-chunks
  const int t = threadIdx.x;
  const int w = t >> 6;
  const int l = t & 63;
  const int wrow = w >> 1, wcol = w & 1;
  const int l16 = l & 15, lq = l >> 4;

  const int row_s = t >> 1;  // scan: thread's row within tile
  const int hv = t & 1;      // scan: which 16-col half of each phase
  const int irow_g = ib * TI + row_s;

  uint32 heap[CSUB];
#pragma unroll
  for (int s = 0; s < CSUB; ++s) heap[s] = 0xFFFFFFFFu;

  for (int jt = 0; jt < JTILES; ++jt) {
    const int jbase = jc * (Nn / JSPLIT) + jt * TJ;
    __syncthreads();  // previous scan's sqj/d2s reads done
    if (t < TJ) sqj[t] = sq[jbase + t];

    f32x4 acc[4][4];
#pragma unroll
    for (int a = 0; a < 4; ++a)
#pragma unroll
      for (int b = 0; b < 4; ++b) acc[a][b] = (f32x4){0.f, 0.f, 0.f, 0.f};

    for (int kk = 0; kk < Dd / BKc; ++kk) {
      __syncthreads();  // LDS reads of previous chunk done
#pragma unroll
      for (int u = 0; u < 4; ++u) {
        const int ch = w * 4 + u;          // wave-uniform chunk id (1KB each)
        const int r = ch * 8 + (l >> 3);   // row within tile
        const int cs = ((l & 7) ^ (r & 7)) * 8;  // pre-swizzled source col (bf16)
        gload_lds16(xb + (size_t)(ib * TI + r) * Dd + kk * BKc + cs,
                    (void*)(ALds + ch * 512));
        gload_lds16(xb + (size_t)(jbase + r) * Dd + kk * BKc + cs,
                    (void*)(BLds + ch * 512));
      }
      __syncthreads();  // staging complete
#pragma unroll
      for (int ks = 0; ks < 2; ++ks) {
        bf16x8 af[4], bfr[4];
#pragma unroll
        for (int fi = 0; fi < 4; ++fi) {
          const int R = wrow * 64 + fi * 16 + l16;
          af[fi] = *(const bf16x8*)&ALds[R * BKc +
                                         ((ks * 32 + lq * 8) ^ ((R & 7) * 8))];
        }
#pragma unroll
        for (int fj = 0; fj < 4; ++fj) {
          const int R = wcol * 64 + fj * 16 + l16;
          bfr[fj] = *(const bf16x8*)&BLds[R * BKc +
                                          ((ks * 32 + lq * 8) ^ ((R & 7) * 8))];
        }
#pragma unroll
        for (int fi = 0; fi < 4; ++fi)
#pragma unroll
          for (int fj = 0; fj < 4; ++fj)
            acc[fi][fj] = __builtin_amdgcn_mfma_f32_16x16x32_bf16(
                af[fi], bfr[fj], acc[fi][fj], 0, 0, 0);
      }
    }

    // Four 32-col phases: stage dot products to LDS (chunk-swizzled), scan.
#pragma unroll
    for (int p = 0; p < 4; ++p) {
      __syncthreads();  // previous phase's scan reads done
      if (wcol == (p >> 1)) {
        const int fjp = p & 1;
#pragma unroll
        for (int fi = 0; fi < 4; ++fi)
#pragma unroll
          for (int fjh = 0; fjh < 2; ++fjh) {
            const int fj = fjp * 2 + fjh;
#pragma unroll
            for (int r = 0; r < 4; ++r) {
              const int row = wrow * 64 + fi * 16 + lq * 4 + r;
              const int c = fjh * 16 + l16;
              const int cs2 = (((c >> 2) ^ (row & 7)) << 2) | (c & 3);
              d2s[row][cs2] = acc[fi][fj][r];
            }
          }
      }
      __syncthreads();
      const uint32 jg0 = (uint32)(jbase + p * 32 + hv * 16);
#pragma unroll
      for (int u2 = 0; u2 < 4; ++u2) {
        const int chunk = (hv * 4 + u2) ^ (row_s & 7);
        float4 v = *(const float4*)&d2s[row_s][chunk * 4];
        float vv[4] = {v.x, v.y, v.z, v.w};
#pragma unroll
        for (int e = 0; e < 4; ++e) {
          const int jj = hv * 16 + u2 * 4 + e;
          // key = d2 - sq_i (row-constant dropped) = sq_j - 2*dot; clamp >=0
          float key = fmaxf(fmaf(-2.f, vv[e], sqj[p * 32 + jj]), 0.f);
          uint32 packed = (__builtin_bit_cast(uint32, key) & 0xFFFFE000u) |
                          (jg0 + (uint32)(u2 * 4 + e));
          topk_insert<CSUB>(heap, packed);  // self removed later in merge
        }
      }
    }
  }

  const int part = (jc * 2 + hv) * 2 + (row_s & 1);  // spread; any bijection ok
  // Simpler deterministic layout: substream id = jc*2+hv, 16 entries each, but
  // we have 32 substreams worth of slots (PART_ENTRIES=512). Use jc*2+hv directly:
  const int sub = jc * 2 + hv;  // 0..15
  (void)part;
#pragma unroll
  for (int s = 0; s < CSUB; ++s)
    partials[(size_t)(sub * CSUB + s) * Nn + irow_g] = heap[s];
}

// ---------------- Kernel C: merge partial lists -> top-32 per row ----------------
__global__ void knn_merge(const uint32* __restrict__ partials,
                          int* __restrict__ cand) {
  __shared__ uint32 xch[128][CC];  // 16 KB
  const int t = threadIdx.x;
  const int r = t >> 1, half = t & 1;
  const int row = blockIdx.x * 128 + r;
  const int TOT = NPART * CSUB;  // 256 entries per row
  uint32 heap[CC];
#pragma unroll
  for (int s = 0; s < CC; ++s) heap[s] = 0xFFFFFFFFu;
  const int e0 = half * (TOT / 2);
  for (int e = 0; e < TOT / 2; ++e) {
    uint32 v = partials[(size_t)(e0 + e) * Nn + row];
    if ((v & 0x1FFFu) == (uint32)row) v = 0xFFFFFFFFu;  // drop self
    topk_insert<CC>(heap, v);
  }
  if (half) {
#pragma unroll
    for (int s = 0; s < CC; ++s) xch[r][s] = heap[s];
  }
  __syncthreads();
  if (!half) {
#pragma unroll
    for (int s = 0; s < CC; ++s) topk_insert<CC>(heap, xch[r][s]);
#pragma unroll
    for (int s = 0; s < CC; ++s)
      cand[(size_t)row * CC + s] = (int)(heap[s] & 0x1FFFu);
  }
}

// ------- Kernel D: exact fp64 rescore of 32 candidates -> top-16 -> average -------
__global__ __launch_bounds__(256) void knn_rescore(
    const float* __restrict__ x, const int* __restrict__ cand,
    float* __restrict__ out) {
  __shared__ int candS[CC];
  __shared__ double d2S[CC];
  __shared__ int selS[KK];
  const int row = blockIdx.x;
  const int t = threadIdx.x, w = t >> 6, l = t & 63;
  if (t < CC) candS[t] = cand[(size_t)row * CC + t];
  __syncthreads();
  const float4* x4 = (const float4*)x;
  float4 xi0 = x4[(size_t)row * 128 + l];
  float4 xi1 = x4[(size_t)row * 128 + 64 + l];
#pragma unroll
  for (int u = 0; u < 8; ++u) {
    const int c = w * 8 + u;
    const int j = candS[c];
    float4 b0 = x4[(size_t)j * 128 + l];
    float4 b1 = x4[(size_t)j * 128 + 64 + l];
    double s = 0.0;
    double d0 = (double)xi0.x - (double)b0.x;
    double d1 = (double)xi0.y - (double)b0.y;
    double d2 = (double)xi0.z - (double)b0.z;
    double d3 = (double)xi0.w - (double)b0.w;
    s = fma(d0, d0, s); s = fma(d1, d1, s); s = fma(d2, d2, s); s = fma(d3, d3, s);
    d0 = (double)xi1.x - (double)b1.x;
    d1 = (double)xi1.y - (double)b1.y;
    d2 = (double)xi1.z - (double)b1.z;
    d3 = (double)xi1.w - (double)b1.w;
    s = fma(d0, d0, s); s = fma(d1, d1, s); s = fma(d2, d2, s); s = fma(d3, d3, s);
#pragma unroll
    for (int off = 32; off > 0; off >>= 1) s += __shfl_down(s, off);
    if (l == 0) d2S[c] = s;
  }
  __syncthreads();
  if (t < CC) {
    const double mine = d2S[t];
    const int mi = candS[t];
    int rank = 0;
#pragma unroll
    for (int o = 0; o < CC; ++o) {
      double vo = d2S[o];
      int io = candS[o];
      if (vo < mine || (vo == mine && io < mi)) rank++;
    }
    if (rank < KK) selS[rank] = mi;
  }
  __syncthreads();
  const float2* x2 = (const float2*)x;
  float ax = 0.f, ay = 0.f;
#pragma unroll
  for (int n = 0; n < KK; ++n) {
    float2 vb = x2[(size_t)selS[n] * 256 + t];
    ax += vb.x;
    ay += vb.y;
  }
  float2* out2 = (float2*)out;
  out2[(size_t)row * 256 + t] = make_float2(ax * 0.0625f, ay * 0.0625f);
}

extern "C" void kernel_launch(void* const* d_in, const int* in_sizes, int n_in,
                              void* d_out, int out_size, void* d_ws,
                              size_t ws_size, hipStream_t stream) {
  const float* x = (const float*)d_in[0];
  float* out = (float*)d_out;
  char* ws = (char*)d_ws;
  // ws layout: xb (8MB) | sq (32KB) | partials (8MB) | cand (1MB)
  unsigned short* xb = (unsigned short*)ws;
  float* sq = (float*)(ws + (size_t)Nn * Dd * 2);
  uint32* partials = (uint32*)(ws + (size_t)Nn * Dd * 2 + (size_t)Nn * 4);
  int* cand = (int*)((char*)partials + (size_t)NPART * CSUB * Nn * 4);

  knn_prep<<<Nn / 4, 256, 0, stream>>>(x, (uint32*)xb, sq);
  knn_cand<<<64 * JSPLIT, 256, 0, stream>>>(xb, sq, partials);
  knn_merge<<<Nn / 128, 256, 0, stream>>>(partials, cand);
  knn_rescore<<<Nn, 256, 0, stream>>>(x, cand, out);
}

// Round 4
// 204.881 us; speedup vs baseline: 2.5400x; 1.4252x over previous
//
#include <hip/hip_runtime.h>
#include <hip/hip_bf16.h>

#define Nn 8192
#define Dd 512
#define KK 16
#define CC 32      // merged candidates per row (rescore input)
#define CSUB 16    // candidates kept per substream reservoir
#define TI 128
#define TJ 128
#define BKc 64
#define JSPLIT 8   // == number of XCDs; jc = bid & 7 -> one B-chunk per XCD
#define JTILES (Nn / JSPLIT / TJ)   // 8
#define NPART (JSPLIT * 2)          // 16 substreams per row
#define PENT (NPART * CSUB)         // 256 partial entries per row

typedef short bf16x8 __attribute__((ext_vector_type(8)));
typedef float f32x4 __attribute__((ext_vector_type(4)));
typedef unsigned int uint32;

__device__ __forceinline__ uint32 med3u(uint32 a, uint32 b, uint32 c) {
  uint32 d;
  asm("v_med3_u32 %0, %1, %2, %3" : "=v"(d) : "v"(a), "v"(b), "v"(c));
  return d;
}

// Branchless top-k (smallest keys) in a descending-sorted register array.
template <int CCn>
__device__ __forceinline__ void topk_insert(uint32* h, uint32 v) {
#pragma unroll
  for (int s = 0; s < CCn - 1; ++s) h[s] = med3u(h[s], h[s + 1], v);
  h[CCn - 1] = (h[CCn - 1] < v) ? h[CCn - 1] : v;
}

__device__ __forceinline__ void gload_lds16(const void* g, void* l) {
  __builtin_amdgcn_global_load_lds(
      (const __attribute__((address_space(1))) unsigned int*)g,
      (__attribute__((address_space(3))) unsigned int*)l, 16, 0, 0);
}

// ---------------- Kernel A: fp32 -> bf16 copy + row sq-norms ----------------
__global__ void knn_prep(const float* __restrict__ x, uint32* __restrict__ xbu,
                         float* __restrict__ sq) {
  const int row = blockIdx.x * 4 + (threadIdx.x >> 6);
  const int l = threadIdx.x & 63;
  const float2* xr = (const float2*)(x + (size_t)row * Dd);
  float s = 0.f;
#pragma unroll
  for (int q = 0; q < 4; ++q) {
    float2 v = xr[q * 64 + l];
    s = fmaf(v.x, v.x, s);
    s = fmaf(v.y, v.y, s);
    uint32 ux = __builtin_bit_cast(uint32, v.x);
    uint32 uy = __builtin_bit_cast(uint32, v.y);
    uint32 bx = (ux + 0x7FFFu + ((ux >> 16) & 1u)) >> 16;  // RNE to bf16
    uint32 by = (uy + 0x7FFFu + ((uy >> 16) & 1u)) >> 16;
    xbu[(size_t)row * (Dd / 2) + q * 64 + l] = bx | (by << 16);
  }
#pragma unroll
  for (int off = 32; off > 0; off >>= 1) s += __shfl_down(s, off);
  if (l == 0) sq[row] = s;
}

// ------- Kernel B: pipelined bf16-MFMA Gram tile + per-substream top-16 -------
// Double-buffered LDS with STAGE(kk+1)-before-compute(kk), one barrier per kk.
// d2s aliases stage[1] (free during scan: in-flight cross-jt prefetch is buf0).
__global__ __launch_bounds__(256, 2) void knn_cand(
    const unsigned short* __restrict__ xb, const float* __restrict__ sq,
    uint32* __restrict__ partials) {
  __shared__ __align__(16) unsigned short stageS[2][TI * BKc * 2];  // 64 KB
  __shared__ float sqj[TJ];

  const int bid = blockIdx.x;
  const int jc = bid & 7;   // XCD-owned J-chunk (bid%8 == XCD round-robin)
  const int ib = bid >> 3;  // 64 I-tiles
  const int t = threadIdx.x;
  const int w = t >> 6;
  const int l = t & 63;
  const int wrow = w >> 1, wcol = w & 1;
  const int l16 = l & 15, lq = l >> 4;

  const int row_s = t >> 1;
  const int hv = t & 1;
  const int irow_g = ib * TI + row_s;
  const int arow0 = ib * TI;

  float (*d2s)[32] = (float(*)[32])(void*)stageS[1];

#define STAGE(buf, brow0, kkk)                                              \
  do {                                                                      \
    _Pragma("unroll") for (int u = 0; u < 4; ++u) {                         \
      const int ch = w * 4 + u;                                             \
      const int r = ch * 8 + (l >> 3);                                      \
      const int cs = ((l & 7) ^ (r & 7)) * 8;                               \
      gload_lds16(xb + (size_t)(arow0 + r) * Dd + (kkk)*BKc + cs,           \
                  (void*)(stageS[buf] + ch * 512));                         \
      gload_lds16(xb + (size_t)(brow0 + r) * Dd + (kkk)*BKc + cs,           \
                  (void*)(stageS[buf] + TI * BKc + ch * 512));              \
    }                                                                       \
  } while (0)

  uint32 heap[CSUB];
#pragma unroll
  for (int s = 0; s < CSUB; ++s) heap[s] = 0xFFFFFFFFu;

  const int jbase0 = jc * (Nn / JSPLIT);
  STAGE(0, jbase0, 0);  // prologue: jt=0, kk=0 into buf0

  for (int jt = 0; jt < JTILES; ++jt) {
    const int jbase = jbase0 + jt * TJ;
    __syncthreads();  // [A] drains prologue / cross-jt prefetch; protects d2s reuse

    f32x4 acc[4][4];
#pragma unroll
    for (int a = 0; a < 4; ++a)
#pragma unroll
      for (int b = 0; b < 4; ++b) acc[a][b] = (f32x4){0.f, 0.f, 0.f, 0.f};

#pragma unroll
    for (int kk = 0; kk < Dd / BKc; ++kk) {
      const int cb = kk & 1;
      // prefetch next chunk into the other buffer (overlaps with compute below)
      if (kk < Dd / BKc - 1) {
        STAGE(cb ^ 1, jbase, kk + 1);
      } else if (jt < JTILES - 1) {
        STAGE(cb ^ 1, jbase + TJ, 0);  // cross-jt prefetch (lands during scan)
      }
      const unsigned short* AL = stageS[cb];
      const unsigned short* BLp = stageS[cb] + TI * BKc;
#pragma unroll
      for (int ks = 0; ks < 2; ++ks) {
        bf16x8 af[4], bfr[4];
#pragma unroll
        for (int fi = 0; fi < 4; ++fi) {
          const int R = wrow * 64 + fi * 16 + l16;
          af[fi] = *(const bf16x8*)&AL[R * BKc +
                                       ((ks * 32 + lq * 8) ^ ((R & 7) * 8))];
        }
#pragma unroll
        for (int fj = 0; fj < 4; ++fj) {
          const int R = wcol * 64 + fj * 16 + l16;
          bfr[fj] = *(const bf16x8*)&BLp[R * BKc +
                                         ((ks * 32 + lq * 8) ^ ((R & 7) * 8))];
        }
#pragma unroll
        for (int fi = 0; fi < 4; ++fi)
#pragma unroll
          for (int fj = 0; fj < 4; ++fj)
            acc[fi][fj] = __builtin_amdgcn_mfma_f32_16x16x32_bf16(
                af[fi], bfr[fj], acc[fi][fj], 0, 0, 0);
      }
      __syncthreads();  // [C] drains this kk's prefetch; orders buffer reuse
    }

    if (t < TJ) sqj[t] = sq[jbase + t];

    // Four 32-col phases: stage dots to d2s (aliases buf1, free now), scan.
#pragma unroll
    for (int p = 0; p < 4; ++p) {
      __syncthreads();  // [D] previous phase's scan reads done (+sqj visible)
      if (wcol == (p >> 1)) {
        const int fjp = p & 1;
#pragma unroll
        for (int fi = 0; fi < 4; ++fi)
#pragma unroll
          for (int fjh = 0; fjh < 2; ++fjh) {
            const int fj = fjp * 2 + fjh;
#pragma unroll
            for (int r = 0; r < 4; ++r) {
              const int row = wrow * 64 + fi * 16 + lq * 4 + r;
              const int c = fjh * 16 + l16;
              const int cs2 = (((c >> 2) ^ (row & 7)) << 2) | (c & 3);
              d2s[row][cs2] = acc[fi][fj][r];
            }
          }
      }
      __syncthreads();  // [E] d2s writes visible
      const uint32 jg0 = (uint32)(jbase + p * 32 + hv * 16);
#pragma unroll
      for (int u2 = 0; u2 < 4; ++u2) {
        const int chunk = (hv * 4 + u2) ^ (row_s & 7);
        float4 v = *(const float4*)&d2s[row_s][chunk * 4];
        float vv[4] = {v.x, v.y, v.z, v.w};
#pragma unroll
        for (int e = 0; e < 4; ++e) {
          float key = fmaxf(fmaf(-2.f, vv[e], sqj[p * 32 + hv * 16 + u2 * 4 + e]), 0.f);
          uint32 packed = (__builtin_bit_cast(uint32, key) & 0xFFFFE000u) |
                          (jg0 + (uint32)(u2 * 4 + e));
          topk_insert<CSUB>(heap, packed);  // self removed later in rescore
        }
      }
    }
  }

  const int sub = jc * 2 + hv;  // 0..15
#pragma unroll
  for (int s = 0; s < CSUB; ++s)
    partials[(size_t)irow_g * PENT + sub * CSUB + s] = heap[s];
#undef STAGE
}

// ---- Kernel C: fused merge (bitonic top-32) + exact fp64 rescore + average ----
__global__ __launch_bounds__(256) void knn_rescore(
    const float* __restrict__ x, const uint32* __restrict__ partials,
    float* __restrict__ out) {
  __shared__ uint32 keyS[PENT];  // 1 KB
  __shared__ int candS[CC];
  __shared__ double d2S[CC];
  __shared__ int selS[KK];
  const int row = blockIdx.x;
  const int t = threadIdx.x, w = t >> 6, l = t & 63;

  uint32 v = partials[(size_t)row * PENT + t];
  if ((v & 0x1FFFu) == (uint32)row) v = 0xFFFFFFFFu;  // drop self
  keyS[t] = v;
  __syncthreads();
  // Bitonic sort 256 keys ascending (distinct j per entry -> total order).
  for (int k = 2; k <= PENT; k <<= 1) {
    for (int j = k >> 1; j > 0; j >>= 1) {
      const int ixj = t ^ j;
      if (ixj > t) {
        uint32 a = keyS[t], b = keyS[ixj];
        const bool up = ((t & k) == 0);
        if ((a > b) == up) {
          keyS[t] = b;
          keyS[ixj] = a;
        }
      }
      __syncthreads();
    }
  }
  if (t < CC) candS[t] = (int)(keyS[t] & 0x1FFFu);
  __syncthreads();

  const float4* x4 = (const float4*)x;
  float4 xi0 = x4[(size_t)row * 128 + l];
  float4 xi1 = x4[(size_t)row * 128 + 64 + l];
#pragma unroll
  for (int u = 0; u < 8; ++u) {
    const int c = w * 8 + u;
    const int j = candS[c];
    float4 b0 = x4[(size_t)j * 128 + l];
    float4 b1 = x4[(size_t)j * 128 + 64 + l];
    double s = 0.0;
    double d0 = (double)xi0.x - (double)b0.x;
    double d1 = (double)xi0.y - (double)b0.y;
    double d2 = (double)xi0.z - (double)b0.z;
    double d3 = (double)xi0.w - (double)b0.w;
    s = fma(d0, d0, s); s = fma(d1, d1, s); s = fma(d2, d2, s); s = fma(d3, d3, s);
    d0 = (double)xi1.x - (double)b1.x;
    d1 = (double)xi1.y - (double)b1.y;
    d2 = (double)xi1.z - (double)b1.z;
    d3 = (double)xi1.w - (double)b1.w;
    s = fma(d0, d0, s); s = fma(d1, d1, s); s = fma(d2, d2, s); s = fma(d3, d3, s);
#pragma unroll
    for (int off = 32; off > 0; off >>= 1) s += __shfl_down(s, off);
    if (l == 0) d2S[c] = s;
  }
  __syncthreads();
  if (t < CC) {
    const double mine = d2S[t];
    const int mi = candS[t];
    int rank = 0;
#pragma unroll
    for (int o = 0; o < CC; ++o) {
      double vo = d2S[o];
      int io = candS[o];
      if (vo < mine || (vo == mine && io < mi)) rank++;
    }
    if (rank < KK) selS[rank] = mi;
  }
  __syncthreads();
  const float2* x2 = (const float2*)x;
  float ax = 0.f, ay = 0.f;
#pragma unroll
  for (int n = 0; n < KK; ++n) {
    float2 vb = x2[(size_t)selS[n] * 256 + t];
    ax += vb.x;
    ay += vb.y;
  }
  float2* out2 = (float2*)out;
  out2[(size_t)row * 256 + t] = make_float2(ax * 0.0625f, ay * 0.0625f);
}

extern "C" void kernel_launch(void* const* d_in, const int* in_sizes, int n_in,
                              void* d_out, int out_size, void* d_ws,
                              size_t ws_size, hipStream_t stream) {
  const float* x = (const float*)d_in[0];
  float* out = (float*)d_out;
  char* ws = (char*)d_ws;
  // ws layout: xb (8MB) | sq (32KB) | partials (8MB)
  unsigned short* xb = (unsigned short*)ws;
  float* sq = (float*)(ws + (size_t)Nn * Dd * 2);
  uint32* partials = (uint32*)(ws + (size_t)Nn * Dd * 2 + (size_t)Nn * 4);

  knn_prep<<<Nn / 4, 256, 0, stream>>>(x, (uint32*)xb, sq);
  knn_cand<<<64 * JSPLIT, 256, 0, stream>>>(xb, sq, partials);
  knn_rescore<<<Nn, 256, 0, stream>>>(x, partials, out);
}